// Round 5
// baseline (718.020 us; speedup 1.0000x reference)
//
#include <hip/hip_runtime.h>

typedef unsigned short u16;
typedef __attribute__((ext_vector_type(8))) short bf16x8;
typedef __attribute__((ext_vector_type(4))) float f32x4;

__device__ __forceinline__ u16 f2b(float f) {
  unsigned u = __float_as_uint(f);
  u += 0x7fffu + ((u >> 16) & 1u);
  return (u16)(u >> 16);
}
__device__ __forceinline__ float b2f(u16 v) {
  return __uint_as_float((unsigned)v << 16);
}

// async global -> LDS, 16B per lane. LDS dest wave-uniform base; HW adds lane*16.
__device__ __forceinline__ void gload16(const u16* g, u16* l) {
  __builtin_amdgcn_global_load_lds((__attribute__((address_space(1))) void*)(g),
                                   (__attribute__((address_space(3))) void*)(l), 16, 0, 0);
}

// ---------------- merged prep: cast x->bf16 + all weight transposes ----------------
__global__ __launch_bounds__(256) void prep_k(const float* __restrict__ x, u16* __restrict__ xb,
                                              const float* __restrict__ Wq, const float* __restrict__ Wk,
                                              const float* __restrict__ Wv, const float* __restrict__ Wo,
                                              const float* __restrict__ W1, const float* __restrict__ W2,
                                              u16* __restrict__ Wqkvt, u16* __restrict__ Wot,
                                              u16* __restrict__ W1t, u16* __restrict__ W2t) {
  int bid = blockIdx.x;
  if (bid < 4096) {
    int i = bid * 256 + threadIdx.x;
    float4 v = *(const float4*)(x + (size_t)i * 4);
    ushort4 o = make_ushort4(f2b(v.x), f2b(v.y), f2b(v.z), f2b(v.w));
    *(ushort4*)(xb + (size_t)i * 4) = o;
    return;
  }
  __shared__ float t[32][33];
  int tx = threadIdx.x & 31, ty = threadIdx.x >> 5;
  const float* src;
  u16* dst;
  int bx, by, ldsrc, lddst;
  int r = bid - 4096;
  if (r < 4096) {
    int which = r >> 10, rr = r & 1023;
    bx = rr & 31; by = rr >> 5; ldsrc = 1024; lddst = 1024;
    src = which == 0 ? Wq : which == 1 ? Wk : which == 2 ? Wv : Wo;
    dst = which < 3 ? Wqkvt + (size_t)which * 1048576 : Wot;
  } else if (r < 8192) {
    int rr = r - 4096;
    bx = rr & 127; by = rr >> 7; src = W1; dst = W1t; ldsrc = 4096; lddst = 1024;
  } else {
    int rr = r - 8192;
    bx = rr & 31; by = rr >> 5; src = W2; dst = W2t; ldsrc = 1024; lddst = 4096;
  }
  int c0 = bx * 32, r0 = by * 32;
#pragma unroll
  for (int i = 0; i < 4; ++i)
    t[ty + i * 8][tx] = src[(size_t)(r0 + ty + i * 8) * ldsrc + c0 + tx];
  __syncthreads();
#pragma unroll
  for (int i = 0; i < 4; ++i)
    dst[(size_t)(c0 + ty + i * 8) * lddst + r0 + tx] = f2b(t[tx][ty + i * 8]);
}

// ---------------- V head-transpose: qkv[(b*S+s)*3072 + 2048 + h*64 + d] -> vt[bh][d][s]
__global__ __launch_bounds__(256) void transpose_v_k(const u16* __restrict__ qkv,
                                                     u16* __restrict__ vt) {
  __shared__ u16 t[32][33];
  int z = blockIdx.z;
  int b = z >> 4, h = z & 15;
  int s0 = blockIdx.x * 32, d0 = blockIdx.y * 32;
  int tx = threadIdx.x, ty = threadIdx.y;
  const u16* src = qkv + (size_t)(b * 1024) * 3072 + 2048 + h * 64;
  u16* dst = vt + (size_t)z * 65536;
#pragma unroll
  for (int i = 0; i < 4; ++i)
    t[ty + i * 8][tx] = src[(size_t)(s0 + ty + i * 8) * 3072 + d0 + tx];
  __syncthreads();
#pragma unroll
  for (int i = 0; i < 4; ++i)
    dst[(size_t)(d0 + i * 8 + ty) * 1024 + s0 + tx] = t[tx][ty + i * 8];
}

// ---------------- GEMM (m97 structure, 128 x BN tile, 4 waves) ----------------
template <int BN, int BIAS, int RELU, int SB16, int SF32, int RESID>
__global__ __launch_bounds__(256) void gemm_k(
    const u16* __restrict__ Ab, long aHi, long aLo, int lda,
    const u16* __restrict__ Bt, long bHi, long bLo, int ldb,
    float* __restrict__ Cf, u16* __restrict__ Cb,
    long cHi, long cLo, int ldc,
    const float* __restrict__ bias, const float* __restrict__ biasB,
    const float* __restrict__ biasC, const float* __restrict__ resid,
    int K, int ZD) {
  constexpr int NT = BN / 32;
  constexpr int CB = (BN * 64 * 2) / 1024;
  __shared__ __align__(128) u16 As[128 * 64];
  __shared__ __align__(128) u16 Bs[BN * 64];

  const int tid = threadIdx.x;
  const int lane = tid & 63;
  const int wave = tid >> 6;
  const int waveM = wave >> 1, waveN = wave & 1;
  const int quad = lane >> 4, l16 = lane & 15;

  const int zb = blockIdx.z / ZD, zr = blockIdx.z % ZD;
  const long aOff = zb * aHi + zr * aLo;
  const long bOff = zb * bHi + zr * bLo;
  const long cOff = zb * cHi + zr * cLo;

  const int row0 = blockIdx.y * 128;
  const int col0 = blockIdx.x * BN;

  const int lr = lane >> 3;
  const int lc = (lane & 7) * 8;

  f32x4 acc[4][NT] = {};

  for (int k0 = 0; k0 < K; k0 += 64) {
    const u16* Ag = Ab + aOff + (long)row0 * lda + k0;
    const u16* Bg = Bt + bOff + (long)col0 * ldb + k0;
#pragma unroll
    for (int c = 0; c < 4; ++c) {
      int ch = c * 4 + wave;
      gload16(Ag + (long)(ch * 8 + lr) * lda + lc, &As[ch * 512]);
    }
#pragma unroll
    for (int c = 0; c < CB / 4; ++c) {
      int ch = c * 4 + wave;
      gload16(Bg + (long)(ch * 8 + lr) * ldb + lc, &Bs[ch * 512]);
    }
    __syncthreads();

    bf16x8 af[4][2], bfr[NT][2];
#pragma unroll
    for (int mi = 0; mi < 4; ++mi)
#pragma unroll
      for (int ks = 0; ks < 2; ++ks)
        af[mi][ks] = *(const bf16x8*)&As[(waveM * 64 + mi * 16 + l16) * 64 + ks * 32 + quad * 8];
#pragma unroll
    for (int ni = 0; ni < NT; ++ni)
#pragma unroll
      for (int ks = 0; ks < 2; ++ks)
        bfr[ni][ks] = *(const bf16x8*)&Bs[(waveN * (BN / 2) + ni * 16 + l16) * 64 + ks * 32 + quad * 8];
#pragma unroll
    for (int ks = 0; ks < 2; ++ks)
#pragma unroll
      for (int mi = 0; mi < 4; ++mi)
#pragma unroll
        for (int ni = 0; ni < NT; ++ni)
          acc[mi][ni] = __builtin_amdgcn_mfma_f32_16x16x32_bf16(af[mi][ks], bfr[ni][ks], acc[mi][ni], 0, 0, 0);
    __syncthreads();
  }

#pragma unroll
  for (int ni = 0; ni < NT; ++ni) {
    int col = col0 + waveN * (BN / 2) + ni * 16 + l16;
    float bv = 0.f;
    if (BIAS == 1) bv = bias[col];
    if (BIAS == 3) bv = col < 1024 ? bias[col] : (col < 2048 ? biasB[col - 1024] : biasC[col - 2048]);
#pragma unroll
    for (int mi = 0; mi < 4; ++mi) {
#pragma unroll
      for (int r = 0; r < 4; ++r) {
        int row = row0 + waveM * 64 + mi * 16 + quad * 4 + r;
        float v = acc[mi][ni][r] + bv;
        if (RELU) v = fmaxf(v, 0.f);
        long idx = cOff + (long)row * ldc + col;
        if (RESID) v += resid[idx];
        if (SF32) Cf[idx] = v;
        if (SB16) Cb[idx] = f2b(v);
      }
    }
  }
}

// ---------------- GEMM 256x256, 8 waves, BK=64, double-buffered, counted vmcnt ----------------
// T2 swizzle: LDS linear dest (gload_lds), source col ((lane&7)^(lane>>3))*16B,
// read col ((ks*4+quad)^(row&7))*16B  -- same involution both sides.
// 4 phases per K-tile: each stages 2 chunks of tile t+1, then 16 MFMA on tile t.
// vmcnt(2) + barrier only at phase 0 (publishes all waves' staging of tile t).
template <int BIAS, int RELU, int SB16, int SF32>
__global__ __launch_bounds__(512, 2) void gemm256_k(
    const u16* __restrict__ Ab, int lda,
    const u16* __restrict__ Bt, int ldb,
    float* __restrict__ Cf, u16* __restrict__ Cb, int ldc,
    const float* __restrict__ bias, const float* __restrict__ biasB,
    const float* __restrict__ biasC, int K) {
  __shared__ __align__(128) u16 As[2][16384];  // [buf][256 rows][8 slots][8 elems]
  __shared__ __align__(128) u16 Bs[2][16384];

  const int tid = threadIdx.x;
  const int lane = tid & 63;
  const int w = tid >> 6;           // 0..7
  const int waveM = w >> 2, waveN = w & 3;
  const int quad = lane >> 4, l16 = lane & 15;

  const int row0 = blockIdx.y * 256;
  const int col0 = blockIdx.x * 256;

  const int srow = lane >> 3;                  // row within 8-row group
  const int scol = ((lane & 7) ^ srow) * 8;    // pre-swizzled source col (elems)

  const u16* Ag = Ab + (long)row0 * lda;
  const u16* Bg = Bt + (long)col0 * ldb;

  f32x4 acc[8][4] = {};
  const int NT = K >> 6;

  // prologue: stage tile 0 into buf 0 (8 gloads per wave)
#pragma unroll
  for (int j = 0; j < 4; ++j) {
    gload16(Ag + (long)(j * 64 + w * 8 + srow) * lda + scol, &As[0][j * 4096 + w * 512]);
    gload16(Bg + (long)(j * 64 + w * 8 + srow) * ldb + scol, &Bs[0][j * 4096 + w * 512]);
  }

  for (int kt = 0; kt < NT; ++kt) {
    const int cur = kt & 1;
    const int nxt = cur ^ 1;
    const bool pre = (kt + 1) < NT;
    const u16* An = Ag + ((long)(kt + 1) << 6);
    const u16* Bn = Bg + ((long)(kt + 1) << 6);

    bf16x8 bfr[4][2];

#pragma unroll
    for (int p = 0; p < 4; ++p) {
      // stage chunk p of tile kt+1 (issue BEFORE compute)
      if (pre) {
        gload16(An + (long)(p * 64 + w * 8 + srow) * lda + scol, &As[nxt][p * 4096 + w * 512]);
        gload16(Bn + (long)(p * 64 + w * 8 + srow) * ldb + scol, &Bs[nxt][p * 4096 + w * 512]);
      }
      if (p == 0) {
        // gate: this wave's 8 loads for tile kt landed (2 newest = tile kt+1 chunk 0)
        if (pre) asm volatile("s_waitcnt vmcnt(2)" ::: "memory");
        else     asm volatile("s_waitcnt vmcnt(0)" ::: "memory");
        __builtin_amdgcn_sched_barrier(0);
        __builtin_amdgcn_s_barrier();   // publish all waves' staging of tile kt
        __builtin_amdgcn_sched_barrier(0);
        // B fragments for the whole K-tile (kept in regs across phases)
#pragma unroll
        for (int ni = 0; ni < 4; ++ni) {
          int rb = waveN * 64 + ni * 16 + l16;
#pragma unroll
          for (int ks = 0; ks < 2; ++ks)
            bfr[ni][ks] = *(const bf16x8*)&Bs[cur][rb * 64 + ((ks * 4 + quad) ^ (rb & 7)) * 8];
        }
      }
      // A fragments for this phase's two m-tiles
      bf16x8 af[2][2];
#pragma unroll
      for (int ii = 0; ii < 2; ++ii) {
        int ra = waveM * 128 + (p * 2 + ii) * 16 + l16;
#pragma unroll
        for (int ks = 0; ks < 2; ++ks)
          af[ii][ks] = *(const bf16x8*)&As[cur][ra * 64 + ((ks * 4 + quad) ^ (ra & 7)) * 8];
      }
      __builtin_amdgcn_s_setprio(1);
#pragma unroll
      for (int ks = 0; ks < 2; ++ks)
#pragma unroll
        for (int ii = 0; ii < 2; ++ii)
#pragma unroll
          for (int ni = 0; ni < 4; ++ni)
            acc[p * 2 + ii][ni] = __builtin_amdgcn_mfma_f32_16x16x32_bf16(
                af[ii][ks], bfr[ni][ks], acc[p * 2 + ii][ni], 0, 0, 0);
      __builtin_amdgcn_s_setprio(0);
      __builtin_amdgcn_sched_barrier(0);
      __builtin_amdgcn_s_barrier();
      __builtin_amdgcn_sched_barrier(0);
    }
  }

  // epilogue
#pragma unroll
  for (int ni = 0; ni < 4; ++ni) {
    int col = col0 + waveN * 64 + ni * 16 + l16;
    float bv = 0.f;
    if (BIAS == 1) bv = bias[col];
    if (BIAS == 3) bv = col < 1024 ? bias[col] : (col < 2048 ? biasB[col - 1024] : biasC[col - 2048]);
#pragma unroll
    for (int mi = 0; mi < 8; ++mi) {
#pragma unroll
      for (int r = 0; r < 4; ++r) {
        int row = row0 + waveM * 128 + mi * 16 + quad * 4 + r;
        float v = acc[mi][ni][r] + bv;
        if (RELU) v = fmaxf(v, 0.f);
        long idx = (long)row * ldc + col;
        if (SF32) Cf[idx] = v;
        if (SB16) Cb[idx] = f2b(v);
      }
    }
  }
}

// ---------------- fused attention: QK^T + softmax + PV + both outputs ----------------
__global__ __launch_bounds__(256) void attn_fused_k(const u16* __restrict__ qkvb,
                                                    const u16* __restrict__ vtb,
                                                    float* __restrict__ attn,
                                                    u16* __restrict__ ctxb) {
  __shared__ __align__(128) u16 Ks[128 * 64];
  __shared__ __align__(128) u16 Vs[64 * 128];
  __shared__ __align__(128) u16 Ps[64 * 136];
  __shared__ float invs[64];

  const int tid = threadIdx.x;
  const int lane = tid & 63;
  const int w = tid >> 6;
  const int quad = lane >> 4, l16 = lane & 15;

  const int z = blockIdx.y;
  const int b = z >> 4, h = z & 15;
  const u16* Kt = qkvb + (long)b * 3145728 + 1024 + h * 64;
  const u16* Vt = vtb + (long)z * 65536;

  const int qabs = blockIdx.x * 64 + w * 16 + l16;
  const long qrow = ((long)b * 1024 + qabs) * 3072 + h * 64;

  bf16x8 qf0 = *(const bf16x8*)&qkvb[qrow + quad * 8];
  bf16x8 qf1 = *(const bf16x8*)&qkvb[qrow + 32 + quad * 8];

  unsigned p[8][8][2];
  float rowsum = 0.f;
  f32x4 cacc[4] = {};

  const int klr = lane >> 3;
  const int klc = 8 * ((lane & 7) ^ (lane >> 3));
  const int vrow_in = lane >> 4;

#pragma unroll
  for (int nc = 0; nc < 8; ++nc) {
#pragma unroll
    for (int c = 0; c < 4; ++c) {
      int ch = c * 4 + w;
      gload16(Kt + (long)(nc * 128 + ch * 8 + klr) * 3072 + klc, &Ks[ch * 512]);
    }
#pragma unroll
    for (int c = 0; c < 4; ++c) {
      int ch = c * 4 + w;
      int vr = ch * 4 + vrow_in;
      int vc = 8 * ((lane & 15) ^ (vr & 7));
      gload16(Vt + (long)vr * 1024 + nc * 128 + vc, &Vs[ch * 512]);
    }
    __syncthreads();

#pragma unroll
    for (int mi = 0; mi < 8; ++mi) {
      int R = mi * 16 + l16;
      bf16x8 kf0 = *(const bf16x8*)&Ks[R * 64 + 8 * (quad ^ (l16 & 7))];
      bf16x8 kf1 = *(const bf16x8*)&Ks[R * 64 + 8 * ((4 + quad) ^ (l16 & 7))];
      f32x4 acc = {};
      acc = __builtin_amdgcn_mfma_f32_16x16x32_bf16(kf0, qf0, acc, 0, 0, 0);
      acc = __builtin_amdgcn_mfma_f32_16x16x32_bf16(kf1, qf1, acc, 0, 0, 0);
      float e0 = __expf(acc[0] * 0.125f);
      float e1 = __expf(acc[1] * 0.125f);
      float e2 = __expf(acc[2] * 0.125f);
      float e3 = __expf(acc[3] * 0.125f);
      rowsum += (e0 + e1) + (e2 + e3);
      unsigned p0 = (unsigned)f2b(e0) | ((unsigned)f2b(e1) << 16);
      unsigned p1 = (unsigned)f2b(e2) | ((unsigned)f2b(e3) << 16);
      p[nc][mi][0] = p0;
      p[nc][mi][1] = p1;
      *(uint2*)&Ps[(w * 16 + l16) * 136 + mi * 16 + quad * 4] = make_uint2(p0, p1);
    }
    __syncthreads();

    {
      int VR = w * 16 + l16;
#pragma unroll
      for (int ks = 0; ks < 4; ++ks) {
        bf16x8 vf = *(const bf16x8*)&Vs[VR * 128 + 8 * ((ks * 4 + quad) ^ (l16 & 7))];
#pragma unroll
        for (int ni = 0; ni < 4; ++ni) {
          bf16x8 pf = *(const bf16x8*)&Ps[(ni * 16 + l16) * 136 + ks * 32 + quad * 8];
          cacc[ni] = __builtin_amdgcn_mfma_f32_16x16x32_bf16(vf, pf, cacc[ni], 0, 0, 0);
        }
      }
    }
    __syncthreads();
  }

  rowsum += __shfl_xor(rowsum, 16);
  rowsum += __shfl_xor(rowsum, 32);
  float inv = 1.f / rowsum;
  if (quad == 0) invs[w * 16 + l16] = inv;
  __syncthreads();

  u16* ctx_lds = Ks;
#pragma unroll
  for (int ni = 0; ni < 4; ++ni) {
    float iv = invs[ni * 16 + l16];
    unsigned c01 = (unsigned)f2b(cacc[ni][0] * iv) | ((unsigned)f2b(cacc[ni][1] * iv) << 16);
    unsigned c23 = (unsigned)f2b(cacc[ni][2] * iv) | ((unsigned)f2b(cacc[ni][3] * iv) << 16);
    *(uint2*)&ctx_lds[(ni * 16 + l16) * 72 + w * 16 + quad * 4] = make_uint2(c01, c23);
  }
  __syncthreads();
#pragma unroll
  for (int i = 0; i < 2; ++i) {
    int q = w * 16 + (lane >> 3) + i * 8;
    int d0 = (lane & 7) * 8;
    bf16x8 cv = *(const bf16x8*)&ctx_lds[q * 72 + d0];
    long tok = (long)b * 1024 + blockIdx.x * 64 + q;
    *(bf16x8*)&ctxb[tok * 1024 + h * 64 + d0] = cv;
  }

  const long arow = ((long)z * 1024 + qabs) * 1024;
#pragma unroll
  for (int nc = 0; nc < 8; ++nc) {
#pragma unroll
    for (int mi = 0; mi < 8; ++mi) {
      float4 v;
      v.x = b2f((u16)(p[nc][mi][0] & 0xffff)) * inv;
      v.y = b2f((u16)(p[nc][mi][0] >> 16)) * inv;
      v.z = b2f((u16)(p[nc][mi][1] & 0xffff)) * inv;
      v.w = b2f((u16)(p[nc][mi][1] >> 16)) * inv;
      *(float4*)&attn[arow + nc * 128 + mi * 16 + quad * 4] = v;
    }
  }
}

// ---------------- residual(+)/layernorm, row of 1024 ----------------
template <int WB16, int ADD>
__global__ __launch_bounds__(256) void add_ln_k(const float* __restrict__ xp,
                                                const float* __restrict__ yp,
                                                const float* __restrict__ g,
                                                const float* __restrict__ bta,
                                                float* __restrict__ of,
                                                u16* __restrict__ ob) {
  long row = blockIdx.x;
  int tid = threadIdx.x;
  float4 v = *(const float4*)(xp + row * 1024 + tid * 4);
  if (ADD) {
    const float4 yv = *(const float4*)(yp + row * 1024 + tid * 4);
    v.x += yv.x; v.y += yv.y; v.z += yv.z; v.w += yv.w;
  }
  float s1 = v.x + v.y + v.z + v.w;
  float s2 = v.x * v.x + v.y * v.y + v.z * v.z + v.w * v.w;
#pragma unroll
  for (int d = 32; d > 0; d >>= 1) {
    s1 += __shfl_xor(s1, d);
    s2 += __shfl_xor(s2, d);
  }
  __shared__ float r1[4], r2[4];
  if ((tid & 63) == 0) { r1[tid >> 6] = s1; r2[tid >> 6] = s2; }
  __syncthreads();
  s1 = r1[0] + r1[1] + r1[2] + r1[3];
  s2 = r2[0] + r2[1] + r2[2] + r2[3];
  float mu = s1 * (1.f / 1024.f);
  float var = s2 * (1.f / 1024.f) - mu * mu;
  float rs = rsqrtf(var + 1e-5f);
  float4 gv = *(const float4*)(g + tid * 4);
  float4 bv = *(const float4*)(bta + tid * 4);
  float4 o;
  o.x = (v.x - mu) * rs * gv.x + bv.x;
  o.y = (v.y - mu) * rs * gv.y + bv.y;
  o.z = (v.z - mu) * rs * gv.z + bv.z;
  o.w = (v.w - mu) * rs * gv.w + bv.w;
  *(float4*)(of + row * 1024 + tid * 4) = o;
  if (WB16) {
    ushort4 ov = make_ushort4(f2b(o.x), f2b(o.y), f2b(o.z), f2b(o.w));
    *(ushort4*)(ob + row * 1024 + tid * 4) = ov;
  }
}

extern "C" void kernel_launch(void* const* d_in, const int* in_sizes, int n_in,
                              void* d_out, int out_size, void* d_ws, size_t ws_size,
                              hipStream_t stream) {
  const float* x   = (const float*)d_in[0];
  const float* Wq  = (const float*)d_in[1];
  const float* bq  = (const float*)d_in[2];
  const float* Wk  = (const float*)d_in[3];
  const float* bk  = (const float*)d_in[4];
  const float* Wv  = (const float*)d_in[5];
  const float* bv  = (const float*)d_in[6];
  const float* Wo  = (const float*)d_in[7];
  const float* bo  = (const float*)d_in[8];
  const float* W1  = (const float*)d_in[9];
  const float* b1  = (const float*)d_in[10];
  const float* W2  = (const float*)d_in[11];
  const float* b2  = (const float*)d_in[12];
  const float* g1  = (const float*)d_in[13];
  const float* be1 = (const float*)d_in[14];
  const float* g2  = (const float*)d_in[15];
  const float* be2 = (const float*)d_in[16];

  float* out = (float*)d_out;
  float* attn = out + 4194304LL;  // [4,16,1024,1024] fp32 (post-softmax weights)

  char* w = (char*)d_ws;
  size_t off = 0;
  auto alloc = [&](size_t bytes) {
    void* p = w + off;
    off = (off + bytes + 255) & ~(size_t)255;
    return p;
  };
  u16* xb        = (u16*)alloc(8388608);
  u16* Wqkvt     = (u16*)alloc(6291456);
  u16* Wot       = (u16*)alloc(2097152);
  u16* W1t       = (u16*)alloc(8388608);
  u16* W2t       = (u16*)alloc(8388608);
  u16* qkvb      = (u16*)alloc(25165824);
  u16* vtb       = (u16*)alloc(8388608);
  u16* ctxb      = (u16*)alloc(8388608);
  float* attn_o  = (float*)alloc(16777216);
  float* x1      = (float*)alloc(16777216);
  u16* x1b       = (u16*)alloc(8388608);
  u16* ff1b      = (u16*)alloc(33554432);
  float* ff2     = (float*)alloc(16777216);
  (void)ws_size; (void)in_sizes; (void)n_in; (void)out_size;

  // 1) merged prep
  prep_k<<<16384, 256, 0, stream>>>(x, xb, Wq, Wk, Wv, Wo, W1, W2, Wqkvt, Wot, W1t, W2t);

  // 2) QKV projection: 256x256 8-wave pipeline
  gemm256_k<3, 0, 1, 0><<<dim3(12, 16), 512, 0, stream>>>(
      xb, 1024, Wqkvt, 1024, nullptr, qkvb, 3072, bq, bk, bv, 1024);

  // 3) V head-transpose
  transpose_v_k<<<dim3(32, 2, 64), dim3(32, 8), 0, stream>>>(qkvb, vtb);

  // 4) fused attention
  attn_fused_k<<<dim3(16, 64), 256, 0, stream>>>(qkvb, vtb, attn, ctxb);

  // 5) attn_o = ctx Wo + bo + x
  gemm_k<64, 1, 0, 0, 1, 1><<<dim3(16, 32, 1), 256, 0, stream>>>(
      ctxb, 0, 0, 1024, Wot, 0, 0, 1024,
      attn_o, nullptr, 0, 0, 1024, bo, nullptr, nullptr, x, 1024, 1);

  // 6) x1 = LN(attn_o)
  add_ln_k<1, 0><<<4096, 256, 0, stream>>>(attn_o, nullptr, g1, be1, x1, x1b);

  // 7) ff1 = relu(x1 W1 + b1): 256x256 8-wave pipeline
  gemm256_k<1, 1, 1, 0><<<dim3(16, 16), 512, 0, stream>>>(
      x1b, 1024, W1t, 1024, nullptr, ff1b, 4096, b1, nullptr, nullptr, 1024);

  // 8) ff2 = ff1 W2 + b2 + x1
  gemm_k<64, 1, 0, 0, 1, 1><<<dim3(16, 32, 1), 256, 0, stream>>>(
      ff1b, 0, 0, 4096, W2t, 0, 0, 4096,
      ff2, nullptr, 0, 0, 1024, b2, nullptr, nullptr, x1, 4096, 1);

  // 9) out = LN(ff2)
  add_ln_k<0, 0><<<4096, 256, 0, stream>>>(ff2, nullptr, g2, be2, out, nullptr);
}